// Round 3
// baseline (79.884 us; speedup 1.0000x reference)
//
#include <hip/hip_runtime.h>
#include <stdint.h>

// ReadoutInterpolator — VERIFIED world model (R15/R16 PASS, absmax 0.03125):
//   d_in[0] c: f32 1e6 | d_in[1] ksp_real: f32 8x8192 | d_in[2] ksp_imag: f32 8x8192
//   d_out: f32 16e6 = 64 MB planar-global stack([re, im]):
//     re at [coil*npts + p], im at [8*npts + coil*npts + p]
//
// R20: READ/WRITE PHASE SEPARATION. Post-mortem of R18/R19: occupancy 2x +
// MLP 2x + NT = +1.2 us -> kernel was never latency-bound. Remaining theory:
// (a) NT stores forfeit L2 write-back absorption (~32 MB of the 64 MB output
//     can stay dirty in L2; the next harness poison-fill overwrites those
//     lines without a drain) -> NT reverted to plain stores.
// (b) Mixed read/write HBM traffic: c-loads interleave with the store stream.
//     Fix: with kChunks=128 each thread owns <= 4 quads, so ALL its c data
//     (4 x float4 = 16 VGPR) is prefetched BEFORE the staging barrier. The
//     post-barrier main loop does ZERO global reads: pure LDS gather + VALU +
//     coalesced float4 stores — same shape as the 6.25 TB/s poison fill.
// Grid 1024 blocks = 4/CU (LDS 4 x 32772 B = 131 KB), 32 waves/CU.
// Tap-2 remains elided (w2 == 0). Wrap pad sk[8192]=sk[0] keeps the 2-tap
// gather a single ds_read2_b32.

namespace {
constexpr int kNCoil  = 8;
constexpr int kNOS    = 8192;   // oversampled readout length (power of 2)
constexpr int kBlock  = 512;    // 8 waves/block
constexpr int kChunks = 128;    // 128*8 = 1024 blocks = 4/CU exactly
constexpr int kMaxQ   = 4;      // quads/thread at npts=1e6: ceil(250000/128)=1954 <= 4*512

__device__ __forceinline__ float bf16lo_to_f32(uint32_t u) {
    union { uint32_t u; float f; } v; v.u = u << 16; return v.f;
}
__device__ __forceinline__ float bf16hi_to_f32(uint32_t u) {
    union { uint32_t u; float f; } v; v.u = u & 0xffff0000u; return v.f;
}
__device__ __forceinline__ uint32_t f32_to_bf16_rne(float f) {
    union { float f; uint32_t u; } v; v.f = f;
    return (v.u + 0x7fffu + ((v.u >> 16) & 1u)) >> 16;
}
} // namespace

__global__ __launch_bounds__(kBlock, 8) void ReadoutInterpolator_54030688583962_kernel(
    const float* __restrict__ c,          // float32, npts
    const float* __restrict__ ksp_real,   // float32, 8*8192
    const float* __restrict__ ksp_imag,   // float32, 8*8192
    float* __restrict__ out,              // f32 planar: [re (8*npts) | im (8*npts)]
    int npts,
    int out_f32_max)                      // total f32 slots = out_size
{
    __shared__ uint32_t sk[kNOS + 1];     // +1 wrap pad: sk[8192] = sk[0]

    const int coil = blockIdx.y;
    const int tid  = threadIdx.x;

    const int planeOff = kNCoil * npts;   // imag plane start (f32 elements)
    const int nq     = npts >> 2;                          // 4-point quads
    const int chunkQ = (nq + (int)gridDim.x - 1) / (int)gridDim.x;
    const int q0     = blockIdx.x * chunkQ;
    const int q1     = min(nq, q0 + chunkQ);

    const float4* __restrict__ c4 = (const float4*)c;

    // ---- Phase 0: prefetch this thread's ENTIRE c working set (<= 4 quads).
    // Latency hides under the staging loads + barrier below.
    float4 cv[kMaxQ];
    #pragma unroll
    for (int u = 0; u < kMaxQ; ++u) {
        const int q = q0 + tid + u * kBlock;
        if (q < q1) cv[u] = c4[q];
    }

    // ---- Phase 1: stage coil row into LDS as packed bf16 pairs ----
    {
        const float4* __restrict__ rv = (const float4*)(ksp_real + (size_t)coil * kNOS);
        const float4* __restrict__ iv = (const float4*)(ksp_imag + (size_t)coil * kNOS);
        for (int i = tid; i < kNOS / 4; i += kBlock) {
            const float4 r = rv[i];
            const float4 m = iv[i];
            const int b = i * 4;
            sk[b + 0] = f32_to_bf16_rne(r.x) | (f32_to_bf16_rne(m.x) << 16);
            sk[b + 1] = f32_to_bf16_rne(r.y) | (f32_to_bf16_rne(m.y) << 16);
            sk[b + 2] = f32_to_bf16_rne(r.z) | (f32_to_bf16_rne(m.z) << 16);
            sk[b + 3] = f32_to_bf16_rne(r.w) | (f32_to_bf16_rne(m.w) << 16);
        }
        if (tid == 0) {   // wrap pad, loaded straight from global (no LDS RAW)
            sk[kNOS] = f32_to_bf16_rne(ksp_real[(size_t)coil * kNOS])
                     | (f32_to_bf16_rne(ksp_imag[(size_t)coil * kNOS]) << 16);
        }
    }
    __syncthreads();

    // ---- Phase 2: pure write phase — LDS gather + VALU + coalesced stores,
    // zero global reads.
    auto interp_quad = [&](const float4 cq, const int qq) {
        const float kx[4] = {cq.x * 4.0f, cq.y * 4.0f, cq.z * 4.0f, cq.w * 4.0f};
        float re[4], im[4];
        #pragma unroll
        for (int j = 0; j < 4; ++j) {
            const float f  = floorf(kx[j]);                 // kx >= 0: trunc == floor
            const float d2 = kx[j] - f;                     // exact; in [0, 1)
            const float w0 = 1.0f - d2;
            const float w1 = d2;
            const int i0 = ((int)f) & (kNOS - 1);           // i0+1 may hit the pad
            const uint32_t g0 = sk[i0];
            const uint32_t g1 = sk[i0 + 1];                 // ds_read2_b32 fusion
            re[j] = fmaf(w1, bf16lo_to_f32(g1), w0 * bf16lo_to_f32(g0));
            im[j] = fmaf(w1, bf16hi_to_f32(g1), w0 * bf16hi_to_f32(g0));
        }

        const int rbase = coil * npts + 4 * qq;
        const int ibase = planeOff + rbase;
        if (ibase + 4 <= out_f32_max) {                     // rbase < ibase always
            *((float4*)(out + rbase)) = make_float4(re[0], re[1], re[2], re[3]);
            *((float4*)(out + ibase)) = make_float4(im[0], im[1], im[2], im[3]);
        } else {
            #pragma unroll
            for (int j = 0; j < 4; ++j) {
                if (rbase + j < out_f32_max) out[rbase + j] = re[j];
                if (ibase + j < out_f32_max) out[ibase + j] = im[j];
            }
        }
    };

    #pragma unroll
    for (int u = 0; u < kMaxQ; ++u) {
        const int q = q0 + tid + u * kBlock;
        if (q < q1) interp_quad(cv[u], q);
    }
    // Fallback for chunkQ > kMaxQ*kBlock (never taken at npts = 1e6).
    for (int q = q0 + tid + kMaxQ * kBlock; q < q1; q += kBlock) {
        interp_quad(c4[q], q);
    }

    // ---- Scalar tail (npts % 4 != 0) — last x-block only ----
    if (blockIdx.x == gridDim.x - 1) {
        for (int p = (nq << 2) + tid; p < npts; p += kBlock) {
            const float kxs = c[p] * 4.0f;
            const float f   = floorf(kxs);
            const float d2  = kxs - f;
            const float w0  = 1.0f - d2;
            const float w1  = d2;
            const int i0 = ((int)f) & (kNOS - 1);
            const uint32_t g0 = sk[i0];
            const uint32_t g1 = sk[i0 + 1];
            const float re = fmaf(w1, bf16lo_to_f32(g1), w0 * bf16lo_to_f32(g0));
            const float im = fmaf(w1, bf16hi_to_f32(g1), w0 * bf16hi_to_f32(g0));
            const int rbase = coil * npts + p;
            const int ibase = planeOff + rbase;
            if (rbase < out_f32_max) out[rbase] = re;
            if (ibase < out_f32_max) out[ibase] = im;
        }
    }
}

extern "C" void kernel_launch(void* const* d_in, const int* in_sizes, int n_in,
                              void* d_out, int out_size, void* d_ws, size_t ws_size,
                              hipStream_t stream) {
    const float* c        = (const float*)d_in[0];
    const float* ksp_real = (const float*)d_in[1];
    const float* ksp_imag = (const float*)d_in[2];
    float*       out      = (float*)d_out;

    const int npts = in_sizes[0];   // c is (NPTS, 1) -> NPTS elements

    dim3 grid(kChunks, kNCoil);
    ReadoutInterpolator_54030688583962_kernel<<<grid, kBlock, 0, stream>>>(
        c, ksp_real, ksp_imag, out, npts, out_size);
}

// Round 4
// 78.551 us; speedup vs baseline: 1.0170x; 1.0170x over previous
//
#include <hip/hip_runtime.h>
#include <stdint.h>

// ReadoutInterpolator — VERIFIED world model (R15/R16 PASS, absmax 0.03125):
//   d_in[0] c: f32 1e6 | d_in[1] ksp_real: f32 8x8192 | d_in[2] ksp_imag: f32 8x8192
//   d_out: f32 16e6 = 64 MB planar-global stack([re, im]):
//     re at [coil*npts + p], im at [8*npts + coil*npts + p]
//
// R21: REVERT TO R17 (best measured: 78.0 us). Session findings R18-R20:
//   - 2x occupancy (32 waves/CU via 1024 blocks): null  -> not latency-bound
//   - nontemporal stores: null/slightly negative         -> L2 policy not on path
//   - read/write phase separation (c prefetch to regs):  null -> traffic mix not on path
// All deltas within the +/-1.5 us run-to-run noise of the ~57 us harness
// poison-fills (5 fills @ ~43/14 us, 6.2-6.3 TB/s = achievable HBM ceiling).
// Kernel portion ~20 us vs 10.9 us pure-HBM floor (64 MB write + 4.5 MB read);
// the residual is the scattered 1024-stream planar write pattern vs the
// fill's linear sweep — pinned by the required output layout.
//
// Structure: 512-thr blocks, grid (64, 8) = 512 blocks; coil row staged in
// LDS as packed bf16 re|im pairs (32 KB + wrap pad); x0 via floorf(kx);
// tap-2 elided (w2 == 0); 2-tap gather is a single ds_read2_b32; coalesced
// float4 stores to both planes.

namespace {
constexpr int kNCoil  = 8;
constexpr int kNOS    = 8192;   // oversampled readout length (power of 2)
constexpr int kBlock  = 512;    // 8 waves/block
constexpr int kChunks = 64;     // grid (64, 8) = 512 blocks, zero tail

__device__ __forceinline__ float bf16lo_to_f32(uint32_t u) {
    union { uint32_t u; float f; } v; v.u = u << 16; return v.f;
}
__device__ __forceinline__ float bf16hi_to_f32(uint32_t u) {
    union { uint32_t u; float f; } v; v.u = u & 0xffff0000u; return v.f;
}
__device__ __forceinline__ uint32_t f32_to_bf16_rne(float f) {
    union { float f; uint32_t u; } v; v.f = f;
    return (v.u + 0x7fffu + ((v.u >> 16) & 1u)) >> 16;
}
} // namespace

__global__ __launch_bounds__(kBlock, 8) void ReadoutInterpolator_54030688583962_kernel(
    const float* __restrict__ c,          // float32, npts
    const float* __restrict__ ksp_real,   // float32, 8*8192
    const float* __restrict__ ksp_imag,   // float32, 8*8192
    float* __restrict__ out,              // f32 planar: [re (8*npts) | im (8*npts)]
    int npts,
    int out_f32_max)                      // total f32 slots = out_size
{
    __shared__ uint32_t sk[kNOS + 1];     // +1 wrap pad: sk[8192] = sk[0]

    const int coil = blockIdx.y;
    const int tid  = threadIdx.x;

    // ---- Stage coil row into LDS as packed bf16 pairs (float4 global loads) ----
    {
        const float4* __restrict__ rv = (const float4*)(ksp_real + (size_t)coil * kNOS);
        const float4* __restrict__ iv = (const float4*)(ksp_imag + (size_t)coil * kNOS);
        for (int i = tid; i < kNOS / 4; i += kBlock) {
            const float4 r = rv[i];
            const float4 m = iv[i];
            const int b = i * 4;
            sk[b + 0] = f32_to_bf16_rne(r.x) | (f32_to_bf16_rne(m.x) << 16);
            sk[b + 1] = f32_to_bf16_rne(r.y) | (f32_to_bf16_rne(m.y) << 16);
            sk[b + 2] = f32_to_bf16_rne(r.z) | (f32_to_bf16_rne(m.z) << 16);
            sk[b + 3] = f32_to_bf16_rne(r.w) | (f32_to_bf16_rne(m.w) << 16);
        }
        if (tid == 0) {   // wrap pad, loaded straight from global (no LDS RAW)
            sk[kNOS] = f32_to_bf16_rne(ksp_real[(size_t)coil * kNOS])
                     | (f32_to_bf16_rne(ksp_imag[(size_t)coil * kNOS]) << 16);
        }
    }
    __syncthreads();

    const int planeOff = kNCoil * npts;   // imag plane start (f32 elements)

    const int nq     = npts >> 2;                          // 4-point quads
    const int chunkQ = (nq + (int)gridDim.x - 1) / (int)gridDim.x;
    const int q0     = blockIdx.x * chunkQ;
    const int q1     = min(nq, q0 + chunkQ);

    const float4* __restrict__ c4 = (const float4*)c;

    for (int q = q0 + tid; q < q1; q += kBlock) {
        const float4 cv = c4[q];
        const float kx[4] = {cv.x * 4.0f, cv.y * 4.0f, cv.z * 4.0f, cv.w * 4.0f};

        float re[4], im[4];
        #pragma unroll
        for (int j = 0; j < 4; ++j) {
            const float f  = floorf(kx[j]);                 // kx >= 0: trunc == floor
            const float d2 = kx[j] - f;                     // exact; in [0, 1)
            const float w0 = 1.0f - d2;
            const float w1 = d2;
            const int i0 = ((int)f) & (kNOS - 1);           // i0+1 may hit the pad
            const uint32_t g0 = sk[i0];
            const uint32_t g1 = sk[i0 + 1];                 // ds_read2_b32 fusion
            re[j] = fmaf(w1, bf16lo_to_f32(g1), w0 * bf16lo_to_f32(g0));
            im[j] = fmaf(w1, bf16hi_to_f32(g1), w0 * bf16hi_to_f32(g0));
        }

        // planar-global: re at coil*npts + p, im at planeOff + coil*npts + p
        const int rbase = coil * npts + 4 * q;
        const int ibase = planeOff + rbase;
        if (ibase + 4 <= out_f32_max) {                     // rbase < ibase always
            *((float4*)(out + rbase)) = make_float4(re[0], re[1], re[2], re[3]);
            *((float4*)(out + ibase)) = make_float4(im[0], im[1], im[2], im[3]);
        } else {
            #pragma unroll
            for (int j = 0; j < 4; ++j) {
                if (rbase + j < out_f32_max) out[rbase + j] = re[j];
                if (ibase + j < out_f32_max) out[ibase + j] = im[j];
            }
        }
    }

    // ---- Scalar tail (npts % 4 != 0) — last x-block only ----
    if (blockIdx.x == gridDim.x - 1) {
        for (int p = (nq << 2) + tid; p < npts; p += kBlock) {
            const float kxs = c[p] * 4.0f;
            const float f   = floorf(kxs);
            const float d2  = kxs - f;
            const float w0  = 1.0f - d2;
            const float w1  = d2;
            const int i0 = ((int)f) & (kNOS - 1);
            const uint32_t g0 = sk[i0];
            const uint32_t g1 = sk[i0 + 1];
            const float re = fmaf(w1, bf16lo_to_f32(g1), w0 * bf16lo_to_f32(g0));
            const float im = fmaf(w1, bf16hi_to_f32(g1), w0 * bf16hi_to_f32(g0));
            const int rbase = coil * npts + p;
            const int ibase = planeOff + rbase;
            if (rbase < out_f32_max) out[rbase] = re;
            if (ibase < out_f32_max) out[ibase] = im;
        }
    }
}

extern "C" void kernel_launch(void* const* d_in, const int* in_sizes, int n_in,
                              void* d_out, int out_size, void* d_ws, size_t ws_size,
                              hipStream_t stream) {
    const float* c        = (const float*)d_in[0];
    const float* ksp_real = (const float*)d_in[1];
    const float* ksp_imag = (const float*)d_in[2];
    float*       out      = (float*)d_out;

    const int npts = in_sizes[0];   // c is (NPTS, 1) -> NPTS elements

    dim3 grid(kChunks, kNCoil);
    ReadoutInterpolator_54030688583962_kernel<<<grid, kBlock, 0, stream>>>(
        c, ksp_real, ksp_imag, out, npts, out_size);
}